// Round 13
// baseline (91.289 us; speedup 1.0000x reference)
//
#include <hip/hip_runtime.h>
#include <math.h>

// ---- problem constants (fixed by reference) ----
#define T_TOK 1024
#define H_DIM 768
#define I_DIM 3072
#define E_NUM 8
#define BM    128
#define BN    64
#define BK    64
#define MSLOTS 16    // max m-tiles at BM=128: 8 + 7 = 15
#define KSPLIT2 4    // FFN2 split-K factor
#define CONV_Y 16    // converter slots PREPENDED to FFN1 grid.y
#define NCONVB (48 * CONV_Y)                        // 768 converter blocks
#define CONV_CHUNKS (E_NUM * I_DIM * H_DIM / 8)     // 2359296 8-elem chunks
#define CONV_PER_T (CONV_CHUNKS / (NCONVB * 512))   // 6
#define CVT_BLKS 2304                               // W1 cvt blocks (2 chunks/thr)
#define GATHER_BLKS (T_TOK * (H_DIM / 8) / 512)     // 192

typedef __attribute__((ext_vector_type(8))) short  short8;   // 8 bf16
typedef __attribute__((ext_vector_type(4))) float  f32x4;

__device__ __forceinline__ unsigned short f2bf(float f) {
  union { float f; unsigned u; } a; a.f = f;
  unsigned r = a.u + 0x7FFFu + ((a.u >> 16) & 1u);  // RTNE
  return (unsigned short)(r >> 16);
}
__device__ __forceinline__ float gelu_exact(float x) {
  return 0.5f * x * (1.0f + erff(x * 0.70710678118654752f));
}
// XOR swizzle: row-major [row][BK] bf16 tile -> conflict-free ds_read_b128 (G4).
__device__ __forceinline__ int swz(int row, int k) {
  return row * BK + (k ^ ((row & 7) << 3));
}
// async global->LDS, 16B per lane. LDS dest = wave-uniform base + lane*16.
__device__ __forceinline__ void gll16(const void* g, void* l) {
  __builtin_amdgcn_global_load_lds(
      (const __attribute__((address_space(1))) void*)g,
      (__attribute__((address_space(3))) void*)l, 16, 0, 0);
}
__device__ __forceinline__ short8 cvt8(const float4 a, const float4 b) {
  short8 o;
  o[0] = (short)f2bf(a.x); o[1] = (short)f2bf(a.y);
  o[2] = (short)f2bf(a.z); o[3] = (short)f2bf(a.w);
  o[4] = (short)f2bf(b.x); o[5] = (short)f2bf(b.y);
  o[6] = (short)f2bf(b.z); o[7] = (short)f2bf(b.w);
  return o;
}

// ---- kernel 1: deterministic expert routing (ballot rank) + tile list ----
__global__ __launch_bounds__(1024) void route_kernel(
    const int* __restrict__ eidx, int* __restrict__ perm,
    int* __restrict__ tile_e, int* __restrict__ tile_row,
    int* __restrict__ tile_len, int* __restrict__ ntiles) {
  __shared__ int wcnt[16][E_NUM];
  __shared__ int wpre[16][E_NUM];
  __shared__ int offsh[E_NUM + 1];
  const int t = threadIdx.x;        // 1024
  const int lane = t & 63, wave = t >> 6;
  const int e = eidx[t];
  unsigned long long myMask = 0;
#pragma unroll
  for (int ee = 0; ee < E_NUM; ++ee) {
    unsigned long long m = __ballot(e == ee);
    if (ee == e) myMask = m;
    if (lane == 0) wcnt[wave][ee] = __popcll(m);
  }
  const int rank = __popcll(myMask & ((1ull << lane) - 1ull));
  __syncthreads();
  if (t < 16 * E_NUM) {
    const int w = t >> 3, ee = t & 7;
    int p = 0;
    for (int w2 = 0; w2 < w; ++w2) p += wcnt[w2][ee];
    wpre[w][ee] = p;
  }
  __syncthreads();
  if (t <= E_NUM) {
    int off = 0;
    for (int ee = 0; ee < t; ++ee) off += wpre[15][ee] + wcnt[15][ee];
    offsh[t] = off;
  }
  __syncthreads();
  perm[offsh[e] + wpre[wave][e] + rank] = t;
  if (t == 0) {
    int n = 0;
    for (int ee = 0; ee < E_NUM; ++ee)
      for (int r = offsh[ee]; r < offsh[ee + 1]; r += BM) {
        tile_e[n] = ee; tile_row[n] = r;
        tile_len[n] = min(offsh[ee + 1] - r, BM); ++n;
      }
    *ntiles = n;
    for (int i = n; i < MSLOTS; ++i) { tile_e[i] = 0; tile_row[i] = 0; tile_len[i] = 0; }
  }
}

// ---- kernel 2: fused {W1 f32->bf16 linear cvt} + {gather x into perm order} --
// nCvt = CVT_BLKS (bf path) or 0 (fallback). cvt blocks first, gather appended.
__global__ __launch_bounds__(512) void gather_cvt_kernel(
    const float* __restrict__ x, const int* __restrict__ perm,
    unsigned short* __restrict__ xg,
    const float* __restrict__ W1, unsigned short* __restrict__ w1b, int nCvt) {
  const int b = blockIdx.x;
  const int t = threadIdx.x;
  if (b < nCvt) {                           // W1 conversion: linear in/out
    const float4* s4 = (const float4*)W1;
    short8* d8 = (short8*)w1b;
#pragma unroll
    for (int j = 0; j < 2; ++j) {
      const int idx = j * (CVT_BLKS * 512) + b * 512 + t;
      d8[idx] = cvt8(s4[2 * idx], s4[2 * idx + 1]);
    }
    return;
  }
  const int idx = (b - nCvt) * 512 + t;     // gather
  const int p = idx / (H_DIM / 8);
  const int c = (idx % (H_DIM / 8)) * 8;
  const int tok = perm[p];
  const float* src = x + (size_t)tok * H_DIM + c;
  *(short8*)(xg + (size_t)p * H_DIM + c) =
      cvt8(*(const float4*)(src), *(const float4*)(src + 4));
}

// ---- grouped GEMM, BM=128 x BN=64, 8 waves (4x2, 32x32 each), dbuf LDS ----
// r8 counted-vmcnt pipeline, B read as bf16 u16 (natural layout, L3-hot).
// A via global_load_lds (pre-swizzled source, linear dest, m173).
// IS_FFN1 && B_BF16: grid.y slots [0, CONV_Y) run the overlapped W2 converter
// FIRST (dispatch order!), GEMM tiles at [CONV_Y, CONV_Y + MSLOTS).
template <int N_FULL, int K_FULL, int KLOOP, bool IS_FFN1, bool B_BF16>
__global__ __launch_bounds__(512, 4) void moe_gemm(
    const unsigned short* __restrict__ A,   // [T_TOK][K_FULL] bf16 (perm order)
    const void* __restrict__ Wv,            // [E][K_FULL][N_FULL] f32 or bf16
    const float* __restrict__ bias,         // [E][N_FULL] (FFN1 only)
    const int* __restrict__ tile_e, const int* __restrict__ tile_row,
    const int* __restrict__ tile_len, const int* __restrict__ ntiles,
    unsigned short* __restrict__ out_bf,    // FFN1 out
    float* __restrict__ part,               // FFN2 partials [KSPLIT2][T_TOK][N_FULL]
    const float* __restrict__ convSrc,      // W2 f32 (FFN1 only)
    unsigned short* __restrict__ convDst) { // w2b
  constexpr int KT = KLOOP / BK;            // 12 (even)
  const int tid  = threadIdx.x;
  int slot = blockIdx.y;

  if constexpr (IS_FFN1 && B_BF16) {
    if (slot < CONV_Y) {                    // W2 f32->bf16, dispatched FIRST
      const int cb  = blockIdx.x + 48 * slot;
      const float4* s4 = (const float4*)convSrc;
      short8* d8 = (short8*)convDst;
#pragma unroll
      for (int j = 0; j < CONV_PER_T; ++j) {
        const int idx = j * (NCONVB * 512) + cb * 512 + tid;
        d8[idx] = cvt8(s4[2 * idx], s4[2 * idx + 1]);
      }
      return;
    }
    slot -= CONV_Y;
  }
  if (slot >= *ntiles) return;
  const int e    = tile_e[slot];
  const int row0 = tile_row[slot];
  const int len  = tile_len[slot];
  const int n0   = blockIdx.x * BN;
  const int kbase = blockIdx.z * KLOOP;

  __shared__ unsigned short As[2][BM * BK];   // 2 x 16 KB, linear chunk order
  __shared__ unsigned short Bs[2][BN * BK];   // 2 x  8 KB, [n][k] swizzled

  const int lane = tid & 63;
  const int wave = tid >> 6;
  const int wm = wave >> 1, wn = wave & 1;    // 4x2 waves: 32 rows x 32 cols each
  const int lr = lane & 15;
  const int lk = (lane >> 4) * 8;

  // A gll addressing: pre-swizzled source, linear LDS dest (m173 / r8-proven).
  const unsigned short* agsrc[2];
  int aoff[2];
#pragma unroll
  for (int i = 0; i < 2; ++i) {
    const int c = tid + i * 512;
    const int r = c >> 3, kc = (c & 7) << 3;
    int grow = row0 + r; grow = grow < T_TOK ? grow : (T_TOK - 1);
    agsrc[i] = A + (size_t)grow * K_FULL + kbase + (kc ^ ((r & 7) << 3));
    aoff[i]  = ((tid & ~63) + i * 512) * 8;   // wave-uniform 16B-chunk base
  }
  // B staging: lane = column (coalesced), wave owns 8 k-rows. f32 or u16.
  const int bn_ = tid & 63;                   // col
  const int kb8 = (tid >> 6) * 8;             // row block
  const float* wpF = nullptr; const unsigned short* wpH = nullptr;
  if constexpr (B_BF16)
    wpH = (const unsigned short*)Wv + (size_t)e * K_FULL * N_FULL +
          (size_t)(kbase + kb8) * N_FULL + n0 + bn_;
  else
    wpF = (const float*)Wv + (size_t)e * K_FULL * N_FULL +
          (size_t)(kbase + kb8) * N_FULL + n0 + bn_;

  f32x4 acc[2][2] = {};
  float Xf[8], Yf[8];
  unsigned short Xh[8], Yh[8];

  auto issueA = [&](int kt, int buf) {
#pragma unroll
    for (int i = 0; i < 2; ++i)
      gll16(agsrc[i] + kt * BK, &As[buf][aoff[i]]);
  };
  auto loadB = [&](int kt, float* df, unsigned short* dh) {
#pragma unroll
    for (int j = 0; j < 8; ++j) {
      if constexpr (B_BF16) dh[j] = wpH[(size_t)(kt * BK + j) * N_FULL];
      else                  df[j] = wpF[(size_t)(kt * BK + j) * N_FULL];
    }
  };
  auto writeB = [&](int buf, const float* df, const unsigned short* dh) {
    short8 p;
#pragma unroll
    for (int j = 0; j < 8; ++j)
      p[j] = B_BF16 ? (short)dh[j] : (short)f2bf(df[j]);
    *(short8*)(&Bs[buf][swz(bn_, kb8)]) = p;        // one b128 (r8: 0 conflicts)
  };
  auto mfma_tile = [&](int buf) {
#pragma unroll
    for (int ks = 0; ks < 2; ++ks) {
      const int kp = ks * 32 + lk;
      short8 af[2], bfr[2];
#pragma unroll
      for (int m = 0; m < 2; ++m)
        af[m] = *(const short8*)(&As[buf][swz(wm * 32 + m * 16 + lr, kp)]);
#pragma unroll
      for (int n = 0; n < 2; ++n)
        bfr[n] = *(const short8*)(&Bs[buf][swz(wn * 32 + n * 16 + lr, kp)]);
#pragma unroll
      for (int m = 0; m < 2; ++m)
#pragma unroll
        for (int n = 0; n < 2; ++n)
          acc[m][n] = __builtin_amdgcn_mfma_f32_16x16x32_bf16(af[m], bfr[n], acc[m][n], 0, 0, 0);
    }
  };
  // phase t entry queue (oldest->newest): B(t) x8, A(t) x2, B(t+1) x8.
  // vmcnt(8) drains B(t)+A(t), keeps B(t+1) in flight across the barrier.
  auto phase = [&](int t, int buf, float* cf, unsigned short* ch,
                   bool nextA, bool nextB, bool drain) {
    if (drain) asm volatile("s_waitcnt vmcnt(0)" ::: "memory");
    else       asm volatile("s_waitcnt vmcnt(8)" ::: "memory");
    writeB(buf, cf, ch);
    asm volatile("s_waitcnt lgkmcnt(0)" ::: "memory");
    __builtin_amdgcn_s_barrier();
    __builtin_amdgcn_sched_barrier(0);
    if (nextA) issueA(t + 1, buf ^ 1);
    __builtin_amdgcn_sched_barrier(0);
    if (nextB) loadB(t + 2, cf, ch);     // reuses the set just written to LDS
    __builtin_amdgcn_sched_barrier(0);
    mfma_tile(buf);
  };

  loadB(0, Xf, Xh);
  __builtin_amdgcn_sched_barrier(0);
  issueA(0, 0);
  __builtin_amdgcn_sched_barrier(0);
  loadB(1, Yf, Yh);
#pragma unroll 1
  for (int t = 0; t < KT - 2; t += 2) {
    phase(t,     0, Xf, Xh, true, true, false);
    phase(t + 1, 1, Yf, Yh, true, true, false);
  }
  phase(KT - 2, 0, Xf, Xh, true,  false, false);
  phase(KT - 1, 1, Yf, Yh, false, false, true);

  // epilogue: C/D layout col=lane&15, row=(lane>>4)*4+j  [verified m89]
#pragma unroll
  for (int n = 0; n < 2; ++n) {
    const int gc = n0 + wn * 32 + n * 16 + lr;
    float bv = 0.f;
    if constexpr (IS_FFN1) bv = bias[(size_t)e * N_FULL + gc];
#pragma unroll
    for (int m = 0; m < 2; ++m) {
      const int rbase = wm * 32 + m * 16 + (lane >> 4) * 4;
#pragma unroll
      for (int j = 0; j < 4; ++j) {
        const int rl = rbase + j;
        if (rl < len) {
          if constexpr (IS_FFN1) {
            out_bf[(size_t)(row0 + rl) * N_FULL + gc] = f2bf(gelu_exact(acc[m][n][j] + bv));
          } else {
            part[((size_t)blockIdx.z * T_TOK + row0 + rl) * N_FULL + gc] = acc[m][n][j];
          }
        }
      }
    }
  }
}

// ---- kernel 5: split-K sum + bias2 + residual + LayerNorm ----
__global__ void ln_kernel(const float* __restrict__ part,
                          const float* __restrict__ x,
                          const int* __restrict__ perm,
                          const int* __restrict__ eidx,
                          const float* __restrict__ b2,
                          const float* __restrict__ gamma,
                          const float* __restrict__ beta,
                          float* __restrict__ out) {
  const int p = blockIdx.x;
  const int tid = threadIdx.x;  // 256
  const int t = perm[p];
  const int e = eidx[t];
  float v[3], s = 0.f, ss = 0.f;
#pragma unroll
  for (int i = 0; i < 3; ++i) {
    const int c = tid + i * 256;
    float a = x[(size_t)t * H_DIM + c] + b2[(size_t)e * H_DIM + c];
#pragma unroll
    for (int s4 = 0; s4 < KSPLIT2; ++s4)
      a += part[((size_t)s4 * T_TOK + p) * H_DIM + c];
    v[i] = a; s += a; ss += a * a;
  }
#pragma unroll
  for (int o = 32; o; o >>= 1) { s += __shfl_down(s, o); ss += __shfl_down(ss, o); }
  __shared__ float ps[4], pss[4];
  __shared__ float mu_s, ir_s;
  const int w = tid >> 6;
  if ((tid & 63) == 0) { ps[w] = s; pss[w] = ss; }
  __syncthreads();
  if (tid == 0) {
    const float S = ps[0] + ps[1] + ps[2] + ps[3];
    const float SS = pss[0] + pss[1] + pss[2] + pss[3];
    const float mu = S * (1.0f / H_DIM);
    const float var = SS * (1.0f / H_DIM) - mu * mu;
    mu_s = mu; ir_s = rsqrtf(var + 1e-12f);
  }
  __syncthreads();
  const float mu = mu_s, ir = ir_s;
#pragma unroll
  for (int i = 0; i < 3; ++i) {
    const int c = tid + i * 256;
    out[(size_t)t * H_DIM + c] = (v[i] - mu) * ir * gamma[c] + beta[c];
  }
}

extern "C" void kernel_launch(void* const* d_in, const int* in_sizes, int n_in,
                              void* d_out, int out_size, void* d_ws, size_t ws_size,
                              hipStream_t stream) {
  const float* x     = (const float*)d_in[0];
  const int*   eidx  = (const int*)d_in[1];
  const float* W1    = (const float*)d_in[2];
  const float* b1    = (const float*)d_in[3];
  const float* W2    = (const float*)d_in[4];
  const float* b2    = (const float*)d_in[5];
  const float* gamma = (const float*)d_in[6];
  const float* beta  = (const float*)d_in[7];
  float* out = (float*)d_out;

  char* ws = (char*)d_ws;
  int* perm     = (int*)(ws);
  int* tile_e   = (int*)(ws + 4096);
  int* tile_row = (int*)(ws + 4352);
  int* tile_len = (int*)(ws + 4608);
  int* ntiles   = (int*)(ws + 4864);
  size_t off = 8192;
  unsigned short* xg = (unsigned short*)(ws + off);    off += (size_t)2 * T_TOK * H_DIM;
  unsigned short* inter = (unsigned short*)(ws + off); off += (size_t)2 * T_TOK * I_DIM;
  float* part = (float*)(ws + off);                    off += (size_t)4 * KSPLIT2 * T_TOK * H_DIM;
  unsigned short* w1b = (unsigned short*)(ws + off);   off += (size_t)2 * E_NUM * H_DIM * I_DIM;
  unsigned short* w2b = (unsigned short*)(ws + off);
  const size_t need = off + (size_t)2 * E_NUM * H_DIM * I_DIM;   // ~95.95 MB (fits per r10/r12)
  const bool bf = ws_size >= need;

  route_kernel<<<1, T_TOK, 0, stream>>>(eidx, perm, tile_e, tile_row, tile_len, ntiles);
  if (bf) {
    // fused: W1->bf16 (bulk, dispatched first) + gather (tail blocks)
    gather_cvt_kernel<<<CVT_BLKS + GATHER_BLKS, 512, 0, stream>>>(
        x, perm, xg, W1, w1b, CVT_BLKS);
    // FFN1 (bf16 W1, L3-hot) with W2 converter blocks dispatched FIRST
    moe_gemm<I_DIM, H_DIM, H_DIM, true, true>
        <<<dim3(I_DIM / BN, CONV_Y + MSLOTS, 1), 512, 0, stream>>>(
        xg, w1b, b1, tile_e, tile_row, tile_len, ntiles, inter, nullptr, W2, w2b);
    // FFN2 (bf16 W2, L3-hot)
    moe_gemm<H_DIM, I_DIM, I_DIM / KSPLIT2, false, true>
        <<<dim3(H_DIM / BN, MSLOTS, KSPLIT2), 512, 0, stream>>>(
        inter, w2b, nullptr, tile_e, tile_row, tile_len, ntiles, nullptr, part,
        nullptr, nullptr);
  } else {
    gather_cvt_kernel<<<GATHER_BLKS, 512, 0, stream>>>(x, perm, xg, nullptr, nullptr, 0);
    moe_gemm<I_DIM, H_DIM, H_DIM, true, false>
        <<<dim3(I_DIM / BN, MSLOTS, 1), 512, 0, stream>>>(
        xg, W1, b1, tile_e, tile_row, tile_len, ntiles, inter, nullptr,
        nullptr, nullptr);
    moe_gemm<H_DIM, I_DIM, I_DIM / KSPLIT2, false, false>
        <<<dim3(H_DIM / BN, MSLOTS, KSPLIT2), 512, 0, stream>>>(
        inter, W2, nullptr, tile_e, tile_row, tile_len, ntiles, nullptr, part,
        nullptr, nullptr);
  }
  ln_kernel<<<T_TOK, 256, 0, stream>>>(part, x, perm, eidx, b2, gamma, beta, out);
  (void)in_sizes; (void)n_in; (void)out_size;
}